// Round 6
// baseline (355.026 us; speedup 1.0000x reference)
//
#include <hip/hip_runtime.h>

// GroupedQueryAttention: B=2, S=2048, HIDDEN=2048, NH=16, NKV=4, HD=128, G=4
// R6: attn = 512 blocks (2/CU!) x 4 waves x 32 q-rows; K/V XOR-swizzled LDS dbuf
//     (64 KB); P transposed C-layout->A-operand IN-REGISTER via __shfl (no sP LDS,
//     no lgkmcnt sync, no conflicts). GEMMs: BK=64 + XOR-swizzled tiles (conflict-
//     free frag reads), 2x MFMA per barrier.

#define SEQ    2048
#define HIDDEN 2048

typedef __attribute__((ext_vector_type(8))) short v8s;   // 8 x bf16 (4 VGPRs)
typedef __attribute__((ext_vector_type(4))) float v4f;   // MFMA accumulator

#define MFMA16(a,b,c) __builtin_amdgcn_mfma_f32_16x16x32_bf16((a),(b),(c),0,0,0)

__device__ __forceinline__ ushort f2b(float f){
  unsigned u = __float_as_uint(f);
  u += 0x7fffu + ((u >> 16) & 1u);       // round-to-nearest-even
  return (ushort)(u >> 16);
}

__device__ __forceinline__ void gload16(const void* g, void* l){
  __builtin_amdgcn_global_load_lds((const __attribute__((address_space(1))) void*)g,
                                   (__attribute__((address_space(3))) void*)l, 16, 0, 0);
}

// s_waitcnt immediates (gfx9): vmcnt[3:0]@0, expcnt@4, lgkmcnt@8, vmcnt[5:4]@14
#define WAIT_VM0   0x0F70   // vmcnt(0)

// ---------- fp32 -> bf16, 4 elems/thread ----------
__global__ void k_conv(const float* __restrict__ in, ushort* __restrict__ out, int n){
  int i = (blockIdx.x*256 + threadIdx.x)*4;
  if (i >= n) return;
  float4 f = *(const float4*)(in + i);
  ushort4 u; u.x=f2b(f.x); u.y=f2b(f.y); u.z=f2b(f.z); u.w=f2b(f.w);
  *(ushort4*)(out + i) = u;
}

// ---------- fp32 (rows x cols) -> bf16 (cols x rows), LDS-tiled ----------
__global__ void k_tconv(const float* __restrict__ in, ushort* __restrict__ out,
                        int rows, int cols){
  __shared__ float t[32][33];
  int tx = threadIdx.x & 31, ty = threadIdx.x >> 5;
  int c0 = blockIdx.x*32, r0 = blockIdx.y*32;
#pragma unroll
  for (int i=0;i<4;i++) t[ty+i*8][tx] = in[(size_t)(r0+ty+i*8)*cols + c0+tx];
  __syncthreads();
#pragma unroll
  for (int i=0;i<4;i++) out[(size_t)(c0+ty+i*8)*rows + r0+tx] = f2b(t[tx][ty+i*8]);
}

// ---------- V bf16 (b,s,h,d) -> (b,h,d,s) ----------
__global__ void k_tv(const ushort* __restrict__ vb, ushort* __restrict__ vT){
  __shared__ ushort t[32][33];
  int tx = threadIdx.x & 31, ty = threadIdx.x >> 5;
  int s0 = blockIdx.x*32, d0 = blockIdx.y*32, bh = blockIdx.z;
  int b = bh >> 2, h = bh & 3;
  const ushort* src = vb + (size_t)b*SEQ*512 + h*128;
#pragma unroll
  for (int i=0;i<4;i++) t[ty+i*8][tx] = src[(size_t)(s0+ty+i*8)*512 + d0+tx];
  __syncthreads();
  ushort* dst = vT + (size_t)bh*128*SEQ;
#pragma unroll
  for (int i=0;i<4;i++) dst[(size_t)(d0+ty+i*8)*SEQ + s0+tx] = t[tx][ty+i*8];
}

// ---------- GEMM mainloop: 128x128 tile, BK=64, XOR-swizzled LDS ----------
// LDS word (row, w) [16B words, 8/row] stored at slot w^(row&7); swizzle applied to
// the GLOBAL word index so global_load_lds dst stays lane-contiguous. Frag reads at
// slot (ks*4+quad)^(lm&7) -> 2-way bank access (free).
#define GEMM_MAIN(A_, Bt_, K_)                                                        \
  __shared__ ushort sA[128*64], sB[128*64];                                           \
  const int tid = threadIdx.x, lane = tid & 63, wid = tid >> 6;                       \
  const int wm = wid >> 1, wn = wid & 1, lm = lane & 15, quad = lane >> 4;            \
  const int rowB = blockIdx.y*128, colB = blockIdx.x*128;                             \
  v4f acc[4][4] = {};                                                                 \
  for (int k0 = 0; k0 < (K_); k0 += 64){                                              \
    _Pragma("unroll")                                                                 \
    for (int it=0; it<4; it++){                                                       \
      int c = tid + it*256; int row = c>>3, wg = (c&7)^(row&7);                       \
      gload16((A_)  + (size_t)(rowB+row)*(K_) + k0 + wg*8, (char*)sA + c*16);         \
      gload16((Bt_) + (size_t)(colB+row)*(K_) + k0 + wg*8, (char*)sB + c*16);         \
    }                                                                                 \
    __syncthreads();                                                                  \
    _Pragma("unroll")                                                                 \
    for (int ks=0; ks<2; ks++){                                                       \
      v8s af[4], bfr[4];                                                              \
      _Pragma("unroll")                                                               \
      for (int i=0;i<4;i++){                                                          \
        af[i]  = *(const v8s*)(sA + (wm*64+i*16+lm)*64 + ((ks*4+quad)^(lm&7))*8);     \
        bfr[i] = *(const v8s*)(sB + (wn*64+i*16+lm)*64 + ((ks*4+quad)^(lm&7))*8);     \
      }                                                                               \
      _Pragma("unroll")                                                               \
      for (int i=0;i<4;i++)                                                           \
        _Pragma("unroll")                                                             \
        for (int j=0;j<4;j++) acc[i][j] = MFMA16(af[i], bfr[j], acc[i][j]);           \
    }                                                                                 \
    __syncthreads();                                                                  \
  }

// QKV GEMM: M=4096, N=3072(packed q|k|v), K=2048; epilogue routes + bias + bf16
__global__ __launch_bounds__(256) void k_gemm_qkv(
    const ushort* __restrict__ A, const ushort* __restrict__ Bt,
    const float* __restrict__ bq, const float* __restrict__ bk, const float* __restrict__ bv,
    ushort* __restrict__ qb, ushort* __restrict__ kb, ushort* __restrict__ vb){
  GEMM_MAIN(A, Bt, HIDDEN)
#pragma unroll
  for (int i=0;i<4;i++)
#pragma unroll
  for (int j=0;j<4;j++){
    int col = colB + wn*64 + j*16 + lm;
#pragma unroll
    for (int r=0;r<4;r++){
      int row = rowB + wm*64 + i*16 + quad*4 + r;
      float v = acc[i][j][r];
      if (col < 2048)      qb[(size_t)row*2048 + col]        = f2b(v + bq[col]);
      else if (col < 2560) kb[(size_t)row*512 + (col-2048)]  = f2b(v + bk[col-2048]);
      else                 vb[(size_t)row*512 + (col-2560)]  = f2b(v + bv[col-2560]);
    }
  }
}

// Output GEMM: M=4096, N=2048, K=2048; fp32 out + bias
__global__ __launch_bounds__(256) void k_gemm_out(
    const ushort* __restrict__ A, const ushort* __restrict__ Bt,
    const float* __restrict__ bo, float* __restrict__ out){
  GEMM_MAIN(A, Bt, HIDDEN)
#pragma unroll
  for (int i=0;i<4;i++)
#pragma unroll
  for (int j=0;j<4;j++){
    int col = colB + wn*64 + j*16 + lm;
#pragma unroll
    for (int r=0;r<4;r++){
      int row = rowB + wm*64 + i*16 + quad*4 + r;
      out[(size_t)row*2048 + col] = acc[i][j][r] + bo[col];
    }
  }
}

// ---------- Flash attention R6 ----------
// 512 blocks (2/CU) x 4 waves, 32 q-rows/wave. 32 iters of 64-key tiles.
// K [64key x 128d] / V^T [128d x 64key] XOR-swizzled LDS, double-buffered, ONE
// barrier/iter. No-max-shift softmax. P: C-layout -> A-operand via __shfl only.
__global__ __launch_bounds__(256, 2) void k_attn(
    const ushort* __restrict__ qb, const ushort* __restrict__ kb,
    const ushort* __restrict__ vT, ushort* __restrict__ Ob){
  __shared__ ushort sK[2][64*128];   // word (key,w16) at slot w^(key&15)
  __shared__ ushort sV[2][128*64];   // word (d,w8)   at slot w^(d&7)
  const int tid = threadIdx.x, lane = tid & 63, w = tid >> 6;
  const int lm = lane & 15, quad = lane >> 4, q8 = quad*8;
  const int pair = blockIdx.x & 7;          // b*4+hkv in low bits -> XCD spread
  const int hkv = pair & 3, b = pair >> 2;
  const int qt = (blockIdx.x >> 3) & 15, g = blockIdx.x >> 7;
  const int head = hkv*4 + g;
  const float C = 0.08838834764831845f * 1.4426950408889634f;  // SCALE * log2(e)

  const ushort* kbb = kb + (size_t)b*SEQ*512 + hkv*128;
  const ushort* vbb = vT + (size_t)(b*4+hkv)*128*SEQ;

  const int kk = lane >> 4, ksw = lane & 15;      // K staging: 4 keys/chunk
  const int dd = lane >> 3, vsw = lane & 7;       // V staging: 8 d-rows/chunk

#define STAGE_K(t, buf) { _Pragma("unroll") for (int i=0;i<4;i++){                     \
    int c = w*4 + i; int key = c*4 + kk; int wd = ksw ^ (key & 15);                    \
    gload16(kbb + (size_t)((t)*64 + key)*512 + wd*8, &sK[buf][c*512 + lane*8]); } }
#define STAGE_V(t, buf) { _Pragma("unroll") for (int i=0;i<4;i++){                     \
    int c = w*4 + i; int drow = c*8 + dd; int wd = vsw ^ dd;                           \
    gload16(vbb + (size_t)drow*SEQ + (t)*64 + wd*8, &sV[buf][c*512 + lane*8]); } }

  // Q fragments (B-operand): qrow = qt*128 + w*32 + rb*16 + lm
  v8s qf[2][4];
#pragma unroll
  for (int rb=0; rb<2; rb++)
#pragma unroll
    for (int ks=0; ks<4; ks++)
      qf[rb][ks] = *(const v8s*)(qb + (size_t)(b*SEQ + qt*128 + w*32 + rb*16 + lm)*HIDDEN
                                    + head*128 + ks*32 + q8);

  v4f o[2][8] = {};
  float lreg[2] = {0.f, 0.f};

  STAGE_K(0, 0)
  STAGE_V(0, 0)
  __builtin_amdgcn_s_waitcnt(WAIT_VM0);
  __syncthreads();

  for (int t=0; t<32; t++){
    const int cur = t & 1;
    if (t < 31){ STAGE_K(t+1, cur^1) STAGE_V(t+1, cur^1) }

    // S^T: sacc[rb][kt]; key = kt*16+quad*4+r, qrow = rb*16+lm
    v4f sacc[2][4] = {};
#pragma unroll
    for (int kt=0; kt<4; kt++){
      v8s kf[4];
#pragma unroll
      for (int ks=0; ks<4; ks++)
        kf[ks] = *(const v8s*)(&sK[cur][(kt*16+lm)*128 + ((ks*4+quad)^lm)*8]);
#pragma unroll
      for (int ks=0; ks<4; ks++)
#pragma unroll
        for (int rb=0; rb<2; rb++)
          sacc[rb][kt] = MFMA16(kf[ks], qf[rb][ks], sacc[rb][kt]);
    }

    // softmax (no max-shift) -> packed bf16 pairs pk[rb][kt]
    uint2 pk[2][4];
#pragma unroll
    for (int rb=0; rb<2; rb++){
      float rs = 0.f;
#pragma unroll
      for (int kt=0; kt<4; kt++){
        float p0 = __builtin_amdgcn_exp2f(sacc[rb][kt][0]*C);
        float p1 = __builtin_amdgcn_exp2f(sacc[rb][kt][1]*C);
        float p2 = __builtin_amdgcn_exp2f(sacc[rb][kt][2]*C);
        float p3 = __builtin_amdgcn_exp2f(sacc[rb][kt][3]*C);
        rs += (p0+p1)+(p2+p3);
        pk[rb][kt].x = (unsigned)f2b(p0) | ((unsigned)f2b(p1) << 16);
        pk[rb][kt].y = (unsigned)f2b(p2) | ((unsigned)f2b(p3) << 16);
      }
      lreg[rb] += rs;   // lane covers 16 keys; reduced across quads at end
    }

    // in-register transpose: C-layout pk -> A-operand pa[rb][kc]
    // target lane (lm,quad): qrow=rb*16+lm, keys kc*32+quad*8+{0..7}
    //   low 4 keys from lane (quad&1)*32+lm, high 4 from +16; kt sel by quad>>1
    const int slo = ((quad & 1) << 5) + lm;
    const bool hi = (quad >> 1) != 0;
    v8s pa[2][2];
#pragma unroll
    for (int rb=0; rb<2; rb++)
#pragma unroll
      for (int kc=0; kc<2; kc++){
        union { uint u[4]; v8s s; } pu;
        unsigned ax = __shfl((int)pk[rb][2*kc].x,   slo);
        unsigned ay = __shfl((int)pk[rb][2*kc].y,   slo);
        unsigned bx = __shfl((int)pk[rb][2*kc+1].x, slo);
        unsigned by = __shfl((int)pk[rb][2*kc+1].y, slo);
        unsigned cx = __shfl((int)pk[rb][2*kc].x,   slo+16);
        unsigned cy = __shfl((int)pk[rb][2*kc].y,   slo+16);
        unsigned dx = __shfl((int)pk[rb][2*kc+1].x, slo+16);
        unsigned dy = __shfl((int)pk[rb][2*kc+1].y, slo+16);
        pu.u[0] = hi ? bx : ax;  pu.u[1] = hi ? by : ay;
        pu.u[2] = hi ? dx : cx;  pu.u[3] = hi ? dy : cy;
        pa[rb][kc] = pu.s;
      }

    // O += P V
#pragma unroll
    for (int dt=0; dt<8; dt++){
      v8s vf[2];
#pragma unroll
      for (int kc=0; kc<2; kc++)
        vf[kc] = *(const v8s*)(&sV[cur][(dt*16+lm)*64 + ((kc*4+quad)^(lm&7))*8]);
#pragma unroll
      for (int kc=0; kc<2; kc++)
#pragma unroll
        for (int rb=0; rb<2; rb++)
          o[rb][dt] = MFMA16(pa[rb][kc], vf[kc], o[rb][dt]);
    }

    __builtin_amdgcn_s_waitcnt(WAIT_VM0);   // K/V(t+1) DMA landed
    __syncthreads();                        // all waves done with cur bufs
  }

  // epilogue: reduce l across quads, transpose to C-layout, normalize, write
#pragma unroll
  for (int rb=0; rb<2; rb++){
    float lv = lreg[rb];
    lv += __shfl_xor(lv, 16);
    lv += __shfl_xor(lv, 32);
    float inv[4];
#pragma unroll
    for (int r=0;r<4;r++) inv[r] = 1.0f / __shfl(lv, (lane & 48) + quad*4 + r);
#pragma unroll
    for (int dt=0; dt<8; dt++)
#pragma unroll
      for (int r=0;r<4;r++){
        int row = b*SEQ + qt*128 + w*32 + rb*16 + quad*4 + r;
        int col = head*128 + dt*16 + lm;
        Ob[(size_t)row*HIDDEN + col] = f2b(o[rb][dt][r]*inv[r]);
      }
  }
#undef STAGE_K
#undef STAGE_V
}

extern "C" void kernel_launch(void* const* d_in, const int* in_sizes, int n_in,
                              void* d_out, int out_size, void* d_ws, size_t ws_size,
                              hipStream_t stream){
  const float* x  = (const float*)d_in[0];
  const float* Wq = (const float*)d_in[1];
  const float* bq = (const float*)d_in[2];
  const float* Wk = (const float*)d_in[3];
  const float* bk = (const float*)d_in[4];
  const float* Wv = (const float*)d_in[5];
  const float* bv = (const float*)d_in[6];
  const float* Wo = (const float*)d_in[7];
  const float* bo = (const float*)d_in[8];
  float* out = (float*)d_out;

  // workspace layout (bf16 elems): 41,943,040 ushorts = 83.9 MB
  ushort* xb  = (ushort*)d_ws;        // 4096x2048
  ushort* Wt  = xb  + 8388608;        // 3072x2048  (Wq^T | Wk^T | Wv^T)
  ushort* Wto = Wt  + 6291456;        // 2048x2048  (Wo^T)
  ushort* qb  = Wto + 4194304;        // 4096x2048
  ushort* kb  = qb  + 8388608;        // 4096x512
  ushort* vb  = kb  + 2097152;        // 4096x512
  ushort* vT  = vb  + 2097152;        // (b,h,d,s) 2x4x128x2048
  ushort* Ob  = vT  + 2097152;        // 4096x2048

  k_conv <<<8192, 256, 0, stream>>>(x, xb, 8388608);
  k_tconv<<<dim3(64,64), 256, 0, stream>>>(Wq, Wt, 2048, 2048);
  k_tconv<<<dim3(16,64), 256, 0, stream>>>(Wk, Wt + 4194304, 2048, 512);
  k_tconv<<<dim3(16,64), 256, 0, stream>>>(Wv, Wt + 5242880, 2048, 512);
  k_tconv<<<dim3(64,64), 256, 0, stream>>>(Wo, Wto, 2048, 2048);
  k_gemm_qkv<<<dim3(24,32), 256, 0, stream>>>(xb, Wt, bq, bk, bv, qb, kb, vb);
  k_tv  <<<dim3(64,4,8), 256, 0, stream>>>(vb, vT);
  k_attn<<<512, 256, 0, stream>>>(qb, kb, vT, Ob);
  k_gemm_out<<<dim3(16,32), 256, 0, stream>>>(Ob, Wto, bo, out);
}